// Round 15
// baseline (157.125 us; speedup 1.0000x reference)
//
#include <hip/hip_runtime.h>
#include <hip/hip_cooperative_groups.h>

namespace cg = cooperative_groups;

// GCN 6-layer, N=100k, E=3.2M — Krylov form + binned CSR build.
// v = sum_{k=0..6} c_k * p_k, p_k = A_norm^k 1.
// Round 15: MLP-batched coop gather — per step, load all NS*2 csr indices,
// then all q values (8 independent loads in flight), then reduce. R14's
// per-sweep serialization (load->shfl->load) capped issue at 0.5 loads/cyc/CU.

#define TPB 256
#define NBPAD 400        // >= nb=391 buckets
#define BINE 8192        // edges per binA block
#define CAP 9216         // bucket capacity (mean 8192, sigma ~90)
#define STAGE_CAP 12288  // per-bucket csr LDS stage
#define BATPB 1024       // binA block size

// ---------- init: bucket cursors + overflow counters ----------
__global__ void init_kernel(int* __restrict__ cursor, int nb,
                            int* __restrict__ ovf_cnt, int* __restrict__ csr_ovf_cur) {
    int t = blockIdx.x * blockDim.x + threadIdx.x;
    if (t < nb) cursor[t] = t * CAP;
    if (t == nb) { ovf_cnt[0] = 0; csr_ovf_cur[0] = 0; }
}

// ---------- coefficient chain helper: 8-way i-split, 1024 threads ----------
template <int NK, int DIN>
__device__ void coef_step8(const float* __restrict__ W, const float* __restrict__ bias,
                           const float (*in)[128], float (*out)[128],
                           float (*part)[6][128], int tid) {
    int t = tid & 127, g = tid >> 7;          // 8 i-groups
    const int CH = (DIN + 7) / 8;
    int i0 = g * CH; if (i0 > DIN) i0 = DIN;
    int i1 = i0 + CH; if (i1 > DIN) i1 = DIN;
    float s[NK];
#pragma unroll
    for (int k = 0; k < NK; ++k) s[k] = 0.f;
    if (t < 125) {
#pragma unroll 4
        for (int i = i0; i < i1; ++i) {
            float w = W[i * 125 + t];
#pragma unroll
            for (int k = 0; k < NK; ++k) s[k] += w * in[k][i];
        }
    }
#pragma unroll
    for (int k = 0; k < NK; ++k) part[g][k][t] = s[k];
    __syncthreads();
    if (g == 0 && t < 125) {
#pragma unroll
        for (int k = 0; k < NK; ++k) {
            float acc = part[0][k][t];
#pragma unroll
            for (int gg = 1; gg < 8; ++gg) acc += part[gg][k][t];
            out[k + 1][t] = acc;
        }
        out[0][t] = bias[t];
    }
    __syncthreads();
}

// ---------- binA (+hidden coef block): LDS-staged counting sort ----------
// binned word: (dst&255)<<24 | src (src < 2^24). Blocks 0..nbA-1 bin edges;
// last block runs the coefficient chain.
struct BinSh {
    int cnt[NBPAD];
    int sa[512], sb[512];
    int lbase[NBPAD], gbase[NBPAD], lcur[NBPAD];
    unsigned int stagew[BINE];
    unsigned short sbuck[BINE];
};
struct CoefSh {
    float A[6][128];
    float B[6][128];
    float part[8][6][128];
};
union BinAU { BinSh a; CoefSh cs; };

__global__ __launch_bounds__(BATPB) void binA_kernel(
    const int* __restrict__ src, const int* __restrict__ dst, int E,
    int* __restrict__ cursor, unsigned int* __restrict__ binned,
    unsigned int* __restrict__ ovf_w, unsigned short* __restrict__ ovf_b,
    int* __restrict__ ovf_cnt,
    const float* __restrict__ W1, const float* __restrict__ b1,
    const float* __restrict__ W2, const float* __restrict__ b2,
    const float* __restrict__ W3, const float* __restrict__ b3,
    const float* __restrict__ W4, const float* __restrict__ b4,
    const float* __restrict__ W5, const float* __restrict__ b5,
    const float* __restrict__ W6, const float* __restrict__ b6,
    float* __restrict__ c) {
    __shared__ BinAU u;
    int t = threadIdx.x;
    int nbA = gridDim.x - 1;

    if ((int)blockIdx.x >= nbA) {
        // ---- coefficient chain (8-way i-split, 1024 threads) ----
        if (t < 25) { u.cs.A[1][t] = W1[t]; u.cs.A[0][t] = b1[t]; }
        __syncthreads();
        coef_step8<2, 25>(W2, b2, u.cs.A, u.cs.B, u.cs.part, t);
        coef_step8<3, 125>(W3, b3, u.cs.B, u.cs.A, u.cs.part, t);
        coef_step8<4, 125>(W4, b4, u.cs.A, u.cs.B, u.cs.part, t);
        coef_step8<5, 125>(W5, b5, u.cs.B, u.cs.A, u.cs.part, t);
        int wave = t >> 6, lane = t & 63;
        if (wave < 6) {
            int k = wave;
            float acc = (lane < 125 ? W6[lane] * u.cs.A[k][lane] : 0.f)
                      + (lane + 64 < 125 ? W6[lane + 64] * u.cs.A[k][lane + 64] : 0.f);
            for (int off = 32; off > 0; off >>= 1) acc += __shfl_down(acc, off);
            if (lane == 0) c[k + 1] = acc;
        }
        if (t == 0) c[0] = b6[0];
        return;
    }

    long long base = (long long)blockIdx.x * BINE;
    int ne = (E - base < BINE) ? (int)(E - base) : BINE;

    for (int j = t; j < NBPAD; j += BATPB) u.a.cnt[j] = 0;
    __syncthreads();

    // count phase: int4 loads, dst cached in registers (2 int4 per thread)
    int dv[2][4];
    const int4* d4 = (const int4*)(dst + base);
#pragma unroll
    for (int i = 0; i < 2; ++i) {
        int j4 = t + i * BATPB;
        if ((j4 << 2) + 3 < ne) {
            int4 v = d4[j4];
            dv[i][0] = v.x; dv[i][1] = v.y; dv[i][2] = v.z; dv[i][3] = v.w;
        } else {
#pragma unroll
            for (int cx = 0; cx < 4; ++cx) {
                int j = (j4 << 2) + cx;
                dv[i][cx] = (j < ne) ? dst[base + j] : -1;
            }
        }
#pragma unroll
        for (int cx = 0; cx < 4; ++cx)
            if (dv[i][cx] >= 0) atomicAdd(&u.a.cnt[dv[i][cx] >> 8], 1);
    }
    __syncthreads();
    // Kogge-Stone inclusive scan over 512 (ping-pong)
    for (int j = t; j < 512; j += BATPB) u.a.sa[j] = (j < NBPAD) ? u.a.cnt[j] : 0;
    __syncthreads();
    int* cu = u.a.sa; int* nx = u.a.sb;
    for (int off = 1; off < 512; off <<= 1) {
        for (int j = t; j < 512; j += BATPB) nx[j] = cu[j] + (j >= off ? cu[j - off] : 0);
        __syncthreads();
        int* tmp = cu; cu = nx; nx = tmp;
    }
    for (int j = t; j < NBPAD; j += BATPB) {
        int ex = cu[j] - u.a.cnt[j];
        u.a.lbase[j] = ex;
        u.a.lcur[j] = ex;
        u.a.gbase[j] = u.a.cnt[j] ? atomicAdd(&cursor[j], u.a.cnt[j]) : 0;
    }
    __syncthreads();
    // stage phase: int4 src loads, dst from registers
    const int4* s4 = (const int4*)(src + base);
#pragma unroll
    for (int i = 0; i < 2; ++i) {
        int j4 = t + i * BATPB;
        int sv[4];
        if ((j4 << 2) + 3 < ne) {
            int4 v = s4[j4];
            sv[0] = v.x; sv[1] = v.y; sv[2] = v.z; sv[3] = v.w;
        } else {
#pragma unroll
            for (int cx = 0; cx < 4; ++cx) {
                int j = (j4 << 2) + cx;
                sv[cx] = (j < ne) ? src[base + j] : -1;
            }
        }
#pragma unroll
        for (int cx = 0; cx < 4; ++cx) {
            if (dv[i][cx] >= 0) {
                int bk = dv[i][cx] >> 8;
                int pos = atomicAdd(&u.a.lcur[bk], 1);
                u.a.stagew[pos] = ((unsigned)(dv[i][cx] & 255) << 24) | (unsigned)sv[cx];
                u.a.sbuck[pos] = (unsigned short)bk;
            }
        }
    }
    __syncthreads();
    // coalesced chunk flush with capacity guard (overflow -> lists)
    for (int j = t; j < ne; j += BATPB) {
        int bk = u.a.sbuck[j];
        int pos = u.a.gbase[bk] + (j - u.a.lbase[bk]);
        if (pos < (bk + 1) * CAP) {
            binned[pos] = u.a.stagew[j];
        } else {
            int ov = atomicAdd(ovf_cnt, 1);
            ovf_w[ov] = u.a.stagew[j];
            ovf_b[ov] = (unsigned short)bk;
        }
    }
}

// ---------- csrB: one block per bucket -> rowptr/rowend, dis, csr ----------
__global__ __launch_bounds__(256) void csrB_kernel(
    const unsigned int* __restrict__ binned, const int* __restrict__ cursor,
    const unsigned int* __restrict__ ovf_w, const unsigned short* __restrict__ ovf_b,
    const int* __restrict__ ovf_cnt, int* __restrict__ csr_ovf_cur,
    int nb, int n,
    int* __restrict__ rowptr, int* __restrict__ rowend,
    int* __restrict__ csr, float* __restrict__ dis) {
    __shared__ int deg[256];
    __shared__ int ex[256];
    __shared__ int cur[256];
    __shared__ int stage[STAGE_CAP];
    __shared__ int sh_obase;
    int b = blockIdx.x;
    int t = threadIdx.x;
    int ebase = b * CAP;
    int total = cursor[b] - ebase;            // true bucket size (incl overflow)
    int mainsz = total < CAP ? total : CAP;
    int eend = ebase + mainsz;
    int ovfn = ovf_cnt[0];                    // normally 0
    int gnode = (b << 8) + t;
    deg[t] = 0;
    __syncthreads();
    // deg count: vectorized main region (ebase is 4-aligned: CAP%4==0)
    {
        int a1 = ebase + (mainsz & ~3);
        const uint4* b4 = (const uint4*)(binned + ebase);
        int n4 = (a1 - ebase) >> 2;
        for (int j = t; j < n4; j += 256) {
            uint4 v = b4[j];
            atomicAdd(&deg[v.x >> 24], 1);
            atomicAdd(&deg[v.y >> 24], 1);
            atomicAdd(&deg[v.z >> 24], 1);
            atomicAdd(&deg[v.w >> 24], 1);
        }
        for (int e = a1 + t; e < eend; e += 256) atomicAdd(&deg[binned[e] >> 24], 1);
    }
    for (int i = t; i < ovfn; i += 256)
        if (ovf_b[i] == b) atomicAdd(&deg[ovf_w[i] >> 24], 1);
    __syncthreads();
    int d = deg[t];
    ex[t] = d;
    __syncthreads();
    for (int off = 1; off < 256; off <<= 1) {
        int a = (t >= off) ? ex[t - off] : 0;
        __syncthreads();
        ex[t] += a;
        __syncthreads();
    }
    int excl = ex[t] - d;
    // output base: gapped main region, or overflow region if oversize
    if (t == 0) {
        if (total <= CAP) sh_obase = ebase;
        else sh_obase = nb * CAP + atomicAdd(csr_ovf_cur, total);
    }
    __syncthreads();
    int obase = sh_obase;
    if (gnode < n) {
        rowptr[gnode] = obase + excl;
        rowend[gnode] = obase + excl + d;
        dis[gnode] = rsqrtf((float)d + 1.0f);   // +1 = self-loop
    }
    cur[t] = excl;
    __syncthreads();
    if (total <= STAGE_CAP) {
        // scatter into LDS stage (vectorized main + overflow), coalesced flush
        {
            int a1 = ebase + (mainsz & ~3);
            const uint4* b4 = (const uint4*)(binned + ebase);
            int n4 = (a1 - ebase) >> 2;
            for (int j = t; j < n4; j += 256) {
                uint4 v = b4[j];
                stage[atomicAdd(&cur[v.x >> 24], 1)] = (int)(v.x & 0xffffffu);
                stage[atomicAdd(&cur[v.y >> 24], 1)] = (int)(v.y & 0xffffffu);
                stage[atomicAdd(&cur[v.z >> 24], 1)] = (int)(v.z & 0xffffffu);
                stage[atomicAdd(&cur[v.w >> 24], 1)] = (int)(v.w & 0xffffffu);
            }
            for (int e = a1 + t; e < eend; e += 256) {
                unsigned int pk = binned[e];
                stage[atomicAdd(&cur[pk >> 24], 1)] = (int)(pk & 0xffffffu);
            }
        }
        for (int i = t; i < ovfn; i += 256) {
            if (ovf_b[i] == b) {
                unsigned int pk = ovf_w[i];
                stage[atomicAdd(&cur[pk >> 24], 1)] = (int)(pk & 0xffffffu);
            }
        }
        __syncthreads();
        for (int e = t; e < total; e += 256) csr[obase + e] = stage[e];
    } else {  // oversize fallback: direct scatter (correct for any input)
        for (int e = ebase + t; e < eend; e += 256) {
            unsigned int pk = binned[e];
            int pos = atomicAdd(&cur[pk >> 24], 1);
            csr[obase + pos] = (int)(pk & 0xffffffu);
        }
        for (int i = t; i < ovfn; i += 256) {
            if (ovf_b[i] == b) {
                unsigned int pk = ovf_w[i];
                int pos = atomicAdd(&cur[pk >> 24], 1);
                csr[obase + pos] = (int)(pk & 0xffffffu);
            }
        }
    }
}

// ---------- cooperative fused gather chain (MLP-batched) ----------
// Per step: batch-load all NS*2 csr indices, then all q values (8 independent
// loads in flight), then reduce. Tail loop covers deg>32. 8 blocks/CU.
template <int NS, int CBT>
__global__ __launch_bounds__(256, 8) void coop_gather_t(
    const int* __restrict__ rowptr, const int* __restrict__ rowend,
    const int* __restrict__ csr,
    const float* __restrict__ dis, float* __restrict__ qA, float* __restrict__ qB,
    const float* __restrict__ c,
    float* __restrict__ bmin, float* __restrict__ bmax,
    float* __restrict__ out, int n) {
    cg::grid_group grid = cg::this_grid();
    __shared__ float smn[256], smx[256];
    int t = threadIdx.x;
    int lane = t & 15, grp = t >> 4;
    int gid0 = (int)blockIdx.x * 16 + grp;       // node id at sweep 0, stride CBT*16

    int beg[NS], end[NS];
    float dd[NS], qown[NS], vacc[NS];
    float cc[7];
#pragma unroll
    for (int k = 0; k < 7; ++k) cc[k] = c[k];

#pragma unroll
    for (int s = 0; s < NS; ++s) {
        int node = gid0 + s * (CBT * 16);
        bool act = node < n;
        beg[s] = act ? rowptr[node] : 0;
        end[s] = act ? rowend[node] : 0;
        dd[s]  = act ? dis[node] : 0.f;
        qown[s] = dd[s];                 // q0 = dis .* ones
        vacc[s] = cc[0];
    }

    const float* q = dis;
    for (int k = 1; k <= 6; ++k) {
        float* qn = (k & 1) ? qA : qB;
        // phase A: batch all csr index loads (independent)
        int ia[NS], ib[NS];
#pragma unroll
        for (int s = 0; s < NS; ++s) {
            int e0 = beg[s] + lane;
            int e1 = e0 + 16;
            ia[s] = (e0 < end[s]) ? csr[e0] : -1;
            ib[s] = (e1 < end[s]) ? csr[e1] : -1;
        }
        // phase B: batch all q gathers (independent)
        float acc[NS];
#pragma unroll
        for (int s = 0; s < NS; ++s) {
            float a0 = (ia[s] >= 0) ? q[ia[s]] : 0.f;
            float a1 = (ib[s] >= 0) ? q[ib[s]] : 0.f;
            acc[s] = a0 + a1;
        }
        // phase C: rare tail (deg > 32)
#pragma unroll
        for (int s = 0; s < NS; ++s) {
            for (int e = beg[s] + 32 + lane; e < end[s]; e += 16)
                acc[s] += q[csr[e]];
        }
        // phase D: reduce + update
#pragma unroll
        for (int s = 0; s < NS; ++s) {
#pragma unroll
            for (int off = 8; off > 0; off >>= 1) acc[s] += __shfl_down(acc[s], off, 16);
            int node = gid0 + s * (CBT * 16);
            if (lane == 0 && node < n) {
                float p = dd[s] * (acc[s] + qown[s]);
                qown[s] = dd[s] * p;
                if (k < 6) qn[node] = qown[s];
                vacc[s] += cc[k] * p;
            }
        }
        if (k < 6) {
            __threadfence();
            grid.sync();
            q = qn;
        }
    }

    // block-local min/max of vacc (lane0s hold real values)
    float mn = 1e30f, mx = -1e30f;
    if (lane == 0) {
#pragma unroll
        for (int s = 0; s < NS; ++s) {
            int node = gid0 + s * (CBT * 16);
            if (node < n) { mn = fminf(mn, vacc[s]); mx = fmaxf(mx, vacc[s]); }
        }
    }
    smn[t] = mn; smx[t] = mx;
    __syncthreads();
    for (int sft = 128; sft > 0; sft >>= 1) {
        if (t < sft) {
            smn[t] = fminf(smn[t], smn[t + sft]);
            smx[t] = fmaxf(smx[t], smx[t + sft]);
        }
        __syncthreads();
    }
    if (t == 0) { bmin[blockIdx.x] = smn[0]; bmax[blockIdx.x] = smx[0]; }
    __threadfence();
    grid.sync();

    // redundant per-block final reduce + normalize
    mn = 1e30f; mx = -1e30f;
    for (int j = t; j < CBT; j += 256) {
        mn = fminf(mn, bmin[j]);
        mx = fmaxf(mx, bmax[j]);
    }
    smn[t] = mn; smx[t] = mx;
    __syncthreads();
    for (int sft = 128; sft > 0; sft >>= 1) {
        if (t < sft) {
            smn[t] = fminf(smn[t], smn[t + sft]);
            smx[t] = fmaxf(smx[t], smx[t + sft]);
        }
        __syncthreads();
    }
    mn = smn[0]; mx = smx[0];
    float inv = 1.0f / (mx - mn + 1e-15f);
    if (lane == 0) {
#pragma unroll
        for (int s = 0; s < NS; ++s) {
            int node = gid0 + s * (CBT * 16);
            if (node < n) out[node] = (vacc[s] - mn) * inv;
        }
    }
}

// ---------- fallback chain (known-good) ----------
__global__ void gather_step(const int* __restrict__ rowptr, const int* __restrict__ rowend,
                            const int* __restrict__ csr,
                            const float* __restrict__ dis, const float* __restrict__ q,
                            const float* __restrict__ c, int k,
                            float* __restrict__ qnext, float* __restrict__ vacc,
                            int n, int first) {
    int tid = blockIdx.x * blockDim.x + threadIdx.x;
    int node = tid >> 4;
    int lane = tid & 15;
    if (node >= n) return;
    int beg = rowptr[node], end = rowend[node];
    float acc = 0.f;
    for (int e = beg + lane; e < end; e += 16) acc += q[csr[e]];
    for (int off = 8; off > 0; off >>= 1) acc += __shfl_down(acc, off, 16);
    if (lane == 0) {
        float d = dis[node];
        float p = d * (acc + q[node]);
        qnext[node] = d * p;
        float add = c[k] * p;
        vacc[node] = first ? (c[0] + add) : (vacc[node] + add);
    }
}

__global__ void gather_last(const int* __restrict__ rowptr, const int* __restrict__ rowend,
                            const int* __restrict__ csr,
                            const float* __restrict__ dis, const float* __restrict__ q,
                            const float* __restrict__ c,
                            float* __restrict__ vacc,
                            float* __restrict__ bmin, float* __restrict__ bmax, int n) {
    __shared__ float smn[TPB], smx[TPB];
    int t = threadIdx.x;
    int tid = blockIdx.x * blockDim.x + t;
    int node = tid >> 4;
    int lane = tid & 15;
    float v = 1e30f;
    bool act = (node < n);
    if (act) {
        int beg = rowptr[node], end = rowend[node];
        float acc = 0.f;
        for (int e = beg + lane; e < end; e += 16) acc += q[csr[e]];
        for (int off = 8; off > 0; off >>= 1) acc += __shfl_down(acc, off, 16);
        if (lane == 0) {
            float d = dis[node];
            float p = d * (acc + q[node]);
            v = vacc[node] + c[6] * p;
            vacc[node] = v;
        }
    }
    smn[t] = (act && lane == 0) ? v : 1e30f;
    smx[t] = (act && lane == 0) ? v : -1e30f;
    __syncthreads();
    for (int s = TPB / 2; s > 0; s >>= 1) {
        if (t < s) { smn[t] = fminf(smn[t], smn[t + s]); smx[t] = fmaxf(smx[t], smx[t + s]); }
        __syncthreads();
    }
    if (t == 0) { bmin[blockIdx.x] = smn[0]; bmax[blockIdx.x] = smx[0]; }
}

__global__ void minmax_final_kernel(const float* __restrict__ bmin, const float* __restrict__ bmax,
                                    int nblk, float* __restrict__ mnmx) {
    __shared__ float smn[TPB], smx[TPB];
    int t = threadIdx.x;
    float mn = 1e30f, mx = -1e30f;
    for (int i = t; i < nblk; i += TPB) {
        mn = fminf(mn, bmin[i]);
        mx = fmaxf(mx, bmax[i]);
    }
    smn[t] = mn; smx[t] = mx;
    __syncthreads();
    for (int s = TPB / 2; s > 0; s >>= 1) {
        if (t < s) { smn[t] = fminf(smn[t], smn[t + s]); smx[t] = fmaxf(smx[t], smx[t + s]); }
        __syncthreads();
    }
    if (t == 0) { mnmx[0] = smn[0]; mnmx[1] = smx[0]; }
}

__global__ void normalize_kernel(const float* __restrict__ v, const float* __restrict__ mnmx,
                                 float* __restrict__ out, int n) {
    int i = blockIdx.x * blockDim.x + threadIdx.x;
    if (i < n) {
        float mn = mnmx[0], mx = mnmx[1];
        out[i] = (v[i] - mn) / (mx - mn + 1e-15f);
    }
}

static inline int cdiv(long long a, int b) { return (int)((a + b - 1) / b); }

extern "C" void kernel_launch(void* const* d_in, const int* in_sizes, int n_in,
                              void* d_out, int out_size, void* d_ws, size_t ws_size,
                              hipStream_t stream) {
    const int N = out_size;               // 100000
    const int E = in_sizes[0] / 2;        // 3200000
    const int* src = (const int*)d_in[0];
    const int* dst = src + E;

    const float* W1 = (const float*)d_in[1];  const float* b1 = (const float*)d_in[2];
    const float* W2 = (const float*)d_in[3];  const float* b2 = (const float*)d_in[4];
    const float* W3 = (const float*)d_in[5];  const float* b3 = (const float*)d_in[6];
    const float* W4 = (const float*)d_in[7];  const float* b4 = (const float*)d_in[8];
    const float* W5 = (const float*)d_in[9];  const float* b5 = (const float*)d_in[10];
    const float* W6 = (const float*)d_in[11]; const float* b6 = (const float*)d_in[12];

    const int nb = (N + 255) >> 8;        // 391 buckets of 256 nodes
    const int gblocks = cdiv((long long)N * 16, TPB);   // 6250
    const size_t nbCAP = (size_t)nb * CAP;

    // workspace layout (16B-aligned arrays first)
    char* p = (char*)d_ws;
    unsigned int* binned = (unsigned int*)p; p += nbCAP * 4;
    int*   csr           = (int*)p;          p += (nbCAP + (size_t)E) * 4;
    unsigned int* ovf_w  = (unsigned int*)p; p += (size_t)E * 4;
    int*   rowptr        = (int*)p;          p += (size_t)N * 4;
    int*   rowend        = (int*)p;          p += (size_t)N * 4;
    float* dis    = (float*)p; p += (size_t)N * 4;
    float* qA     = (float*)p; p += (size_t)N * 4;
    float* qB     = (float*)p; p += (size_t)N * 4;
    float* vacc   = (float*)p; p += (size_t)N * 4;
    float* bmin   = (float*)p; p += (size_t)gblocks * 4;
    float* bmax   = (float*)p; p += (size_t)gblocks * 4;
    float* c      = (float*)p; p += (size_t)8 * 4;
    float* mnmx   = (float*)p; p += 2 * 4;
    int*   cursor = (int*)p;   p += (size_t)512 * 4;
    int*   ovf_cnt = (int*)p;  p += 4;
    int*   csr_ovf_cur = (int*)p; p += 4;
    unsigned short* ovf_b = (unsigned short*)p; p += (size_t)E * 2;

    // ---- CSR build (no hist/scan: fixed-capacity buckets + overflow) ----
    init_kernel<<<2, 256, 0, stream>>>(cursor, nb, ovf_cnt, csr_ovf_cur);
    const int nbA = cdiv(E, BINE);        // 391 binning blocks + 1 coef block
    binA_kernel<<<nbA + 1, BATPB, 0, stream>>>(src, dst, E, cursor, binned,
                                               ovf_w, ovf_b, ovf_cnt,
                                               W1, b1, W2, b2, W3, b3,
                                               W4, b4, W5, b5, W6, b6, c);
    csrB_kernel<<<nb, 256, 0, stream>>>(binned, cursor, ovf_w, ovf_b, ovf_cnt,
                                        csr_ovf_cur, nb, N,
                                        rowptr, rowend, csr, dis);

    // ---- gather chain: coop<4,2048> if 8 blocks/CU fit, else launch chain ----
    constexpr int CB8 = 2048, NS8 = 4;
    int occ = 0;
    hipError_t oerr = hipOccupancyMaxActiveBlocksPerMultiprocessor(
        &occ, (const void*)coop_gather_t<NS8, CB8>, 256, 0);
    bool canCoop = (oerr == hipSuccess) && ((long long)occ * 256 >= CB8) &&
                   (N <= CB8 * 16 * NS8);
    if (canCoop) {
        const int* rp = rowptr; const int* re = rowend; const int* cs = csr;
        const float* dis_c = dis; const float* cc = c;
        float* qA_ = qA; float* qB_ = qB;
        float* bmin_ = bmin; float* bmax_ = bmax;
        float* outp = (float*)d_out;
        int n_ = N;
        void* args[] = { &rp, &re, &cs, &dis_c, &qA_, &qB_, &cc,
                         &bmin_, &bmax_, &outp, &n_ };
        hipLaunchCooperativeKernel((const void*)coop_gather_t<NS8, CB8>,
                                   dim3(CB8), dim3(256), args, 0, stream);
    } else {
        gather_step<<<gblocks, TPB, 0, stream>>>(rowptr, rowend, csr, dis, dis, c, 1, qA, vacc, N, 1);
        gather_step<<<gblocks, TPB, 0, stream>>>(rowptr, rowend, csr, dis, qA,  c, 2, qB, vacc, N, 0);
        gather_step<<<gblocks, TPB, 0, stream>>>(rowptr, rowend, csr, dis, qB,  c, 3, qA, vacc, N, 0);
        gather_step<<<gblocks, TPB, 0, stream>>>(rowptr, rowend, csr, dis, qA,  c, 4, qB, vacc, N, 0);
        gather_step<<<gblocks, TPB, 0, stream>>>(rowptr, rowend, csr, dis, qB,  c, 5, qA, vacc, N, 0);
        gather_last<<<gblocks, TPB, 0, stream>>>(rowptr, rowend, csr, dis, qA, c, vacc, bmin, bmax, N);
        minmax_final_kernel<<<1, TPB, 0, stream>>>(bmin, bmax, gblocks, mnmx);
        normalize_kernel<<<cdiv(N, TPB), TPB, 0, stream>>>(vacc, mnmx, (float*)d_out, N);
    }
}

// Round 16
// 156.708 us; speedup vs baseline: 1.0027x; 1.0027x over previous
//
#include <hip/hip_runtime.h>
#include <hip/hip_cooperative_groups.h>

namespace cg = cooperative_groups;

// GCN 6-layer, N=100k, E=3.2M — Krylov form + binned CSR build.
// v = sum_{k=0..6} c_k * p_k, p_k = A_norm^k 1.
// Round 16: csrB single-pass (register-cached binned words, 512 threads) —
// kills the second 12.8MB binned read. Gather untouched (3 structures
// converged at the L1-MSHR/L2-latency floor, ~14.6us/step).

#define TPB 256
#define NBPAD 400        // >= nb=391 buckets
#define BINE 8192        // edges per binA block
#define CAP 9216         // bucket capacity (mean 8192, sigma ~90)
#define STAGE_CAP 12288  // per-bucket csr LDS stage
#define BATPB 1024       // binA block size

// ---------- init: bucket cursors + overflow counters ----------
__global__ void init_kernel(int* __restrict__ cursor, int nb,
                            int* __restrict__ ovf_cnt, int* __restrict__ csr_ovf_cur) {
    int t = blockIdx.x * blockDim.x + threadIdx.x;
    if (t < nb) cursor[t] = t * CAP;
    if (t == nb) { ovf_cnt[0] = 0; csr_ovf_cur[0] = 0; }
}

// ---------- coefficient chain helper: 8-way i-split, 1024 threads ----------
template <int NK, int DIN>
__device__ void coef_step8(const float* __restrict__ W, const float* __restrict__ bias,
                           const float (*in)[128], float (*out)[128],
                           float (*part)[6][128], int tid) {
    int t = tid & 127, g = tid >> 7;          // 8 i-groups
    const int CH = (DIN + 7) / 8;
    int i0 = g * CH; if (i0 > DIN) i0 = DIN;
    int i1 = i0 + CH; if (i1 > DIN) i1 = DIN;
    float s[NK];
#pragma unroll
    for (int k = 0; k < NK; ++k) s[k] = 0.f;
    if (t < 125) {
#pragma unroll 4
        for (int i = i0; i < i1; ++i) {
            float w = W[i * 125 + t];
#pragma unroll
            for (int k = 0; k < NK; ++k) s[k] += w * in[k][i];
        }
    }
#pragma unroll
    for (int k = 0; k < NK; ++k) part[g][k][t] = s[k];
    __syncthreads();
    if (g == 0 && t < 125) {
#pragma unroll
        for (int k = 0; k < NK; ++k) {
            float acc = part[0][k][t];
#pragma unroll
            for (int gg = 1; gg < 8; ++gg) acc += part[gg][k][t];
            out[k + 1][t] = acc;
        }
        out[0][t] = bias[t];
    }
    __syncthreads();
}

// ---------- binA (+hidden coef block): LDS-staged counting sort ----------
// binned word: (dst&255)<<24 | src (src < 2^24). Blocks 0..nbA-1 bin edges;
// last block runs the coefficient chain.
struct BinSh {
    int cnt[NBPAD];
    int sa[512], sb[512];
    int lbase[NBPAD], gbase[NBPAD], lcur[NBPAD];
    unsigned int stagew[BINE];
    unsigned short sbuck[BINE];
};
struct CoefSh {
    float A[6][128];
    float B[6][128];
    float part[8][6][128];
};
union BinAU { BinSh a; CoefSh cs; };

__global__ __launch_bounds__(BATPB) void binA_kernel(
    const int* __restrict__ src, const int* __restrict__ dst, int E,
    int* __restrict__ cursor, unsigned int* __restrict__ binned,
    unsigned int* __restrict__ ovf_w, unsigned short* __restrict__ ovf_b,
    int* __restrict__ ovf_cnt,
    const float* __restrict__ W1, const float* __restrict__ b1,
    const float* __restrict__ W2, const float* __restrict__ b2,
    const float* __restrict__ W3, const float* __restrict__ b3,
    const float* __restrict__ W4, const float* __restrict__ b4,
    const float* __restrict__ W5, const float* __restrict__ b5,
    const float* __restrict__ W6, const float* __restrict__ b6,
    float* __restrict__ c) {
    __shared__ BinAU u;
    int t = threadIdx.x;
    int nbA = gridDim.x - 1;

    if ((int)blockIdx.x >= nbA) {
        // ---- coefficient chain (8-way i-split, 1024 threads) ----
        if (t < 25) { u.cs.A[1][t] = W1[t]; u.cs.A[0][t] = b1[t]; }
        __syncthreads();
        coef_step8<2, 25>(W2, b2, u.cs.A, u.cs.B, u.cs.part, t);
        coef_step8<3, 125>(W3, b3, u.cs.B, u.cs.A, u.cs.part, t);
        coef_step8<4, 125>(W4, b4, u.cs.A, u.cs.B, u.cs.part, t);
        coef_step8<5, 125>(W5, b5, u.cs.B, u.cs.A, u.cs.part, t);
        int wave = t >> 6, lane = t & 63;
        if (wave < 6) {
            int k = wave;
            float acc = (lane < 125 ? W6[lane] * u.cs.A[k][lane] : 0.f)
                      + (lane + 64 < 125 ? W6[lane + 64] * u.cs.A[k][lane + 64] : 0.f);
            for (int off = 32; off > 0; off >>= 1) acc += __shfl_down(acc, off);
            if (lane == 0) c[k + 1] = acc;
        }
        if (t == 0) c[0] = b6[0];
        return;
    }

    long long base = (long long)blockIdx.x * BINE;
    int ne = (E - base < BINE) ? (int)(E - base) : BINE;

    for (int j = t; j < NBPAD; j += BATPB) u.a.cnt[j] = 0;
    __syncthreads();

    // count phase: int4 loads, dst cached in registers (2 int4 per thread)
    int dv[2][4];
    const int4* d4 = (const int4*)(dst + base);
#pragma unroll
    for (int i = 0; i < 2; ++i) {
        int j4 = t + i * BATPB;
        if ((j4 << 2) + 3 < ne) {
            int4 v = d4[j4];
            dv[i][0] = v.x; dv[i][1] = v.y; dv[i][2] = v.z; dv[i][3] = v.w;
        } else {
#pragma unroll
            for (int cx = 0; cx < 4; ++cx) {
                int j = (j4 << 2) + cx;
                dv[i][cx] = (j < ne) ? dst[base + j] : -1;
            }
        }
#pragma unroll
        for (int cx = 0; cx < 4; ++cx)
            if (dv[i][cx] >= 0) atomicAdd(&u.a.cnt[dv[i][cx] >> 8], 1);
    }
    __syncthreads();
    // Kogge-Stone inclusive scan over 512 (ping-pong)
    for (int j = t; j < 512; j += BATPB) u.a.sa[j] = (j < NBPAD) ? u.a.cnt[j] : 0;
    __syncthreads();
    int* cu = u.a.sa; int* nx = u.a.sb;
    for (int off = 1; off < 512; off <<= 1) {
        for (int j = t; j < 512; j += BATPB) nx[j] = cu[j] + (j >= off ? cu[j - off] : 0);
        __syncthreads();
        int* tmp = cu; cu = nx; nx = tmp;
    }
    for (int j = t; j < NBPAD; j += BATPB) {
        int ex = cu[j] - u.a.cnt[j];
        u.a.lbase[j] = ex;
        u.a.lcur[j] = ex;
        u.a.gbase[j] = u.a.cnt[j] ? atomicAdd(&cursor[j], u.a.cnt[j]) : 0;
    }
    __syncthreads();
    // stage phase: int4 src loads, dst from registers
    const int4* s4 = (const int4*)(src + base);
#pragma unroll
    for (int i = 0; i < 2; ++i) {
        int j4 = t + i * BATPB;
        int sv[4];
        if ((j4 << 2) + 3 < ne) {
            int4 v = s4[j4];
            sv[0] = v.x; sv[1] = v.y; sv[2] = v.z; sv[3] = v.w;
        } else {
#pragma unroll
            for (int cx = 0; cx < 4; ++cx) {
                int j = (j4 << 2) + cx;
                sv[cx] = (j < ne) ? src[base + j] : -1;
            }
        }
#pragma unroll
        for (int cx = 0; cx < 4; ++cx) {
            if (dv[i][cx] >= 0) {
                int bk = dv[i][cx] >> 8;
                int pos = atomicAdd(&u.a.lcur[bk], 1);
                u.a.stagew[pos] = ((unsigned)(dv[i][cx] & 255) << 24) | (unsigned)sv[cx];
                u.a.sbuck[pos] = (unsigned short)bk;
            }
        }
    }
    __syncthreads();
    // coalesced chunk flush with capacity guard (overflow -> lists)
    for (int j = t; j < ne; j += BATPB) {
        int bk = u.a.sbuck[j];
        int pos = u.a.gbase[bk] + (j - u.a.lbase[bk]);
        if (pos < (bk + 1) * CAP) {
            binned[pos] = u.a.stagew[j];
        } else {
            int ov = atomicAdd(ovf_cnt, 1);
            ovf_w[ov] = u.a.stagew[j];
            ovf_b[ov] = (unsigned short)bk;
        }
    }
}

// ---------- csrB: single-pass, reg-cached, 512 threads ----------
// One block per bucket. Reads the bucket's binned words ONCE into registers
// (5 x uint4 per thread covers CAP=9216 <= 10240), deg-counts, scans,
// scatters from registers into the LDS stage, coalesced csr flush.
__global__ __launch_bounds__(512) void csrB_kernel(
    const unsigned int* __restrict__ binned, const int* __restrict__ cursor,
    const unsigned int* __restrict__ ovf_w, const unsigned short* __restrict__ ovf_b,
    const int* __restrict__ ovf_cnt, int* __restrict__ csr_ovf_cur,
    int nb, int n,
    int* __restrict__ rowptr, int* __restrict__ rowend,
    int* __restrict__ csr, float* __restrict__ dis) {
    __shared__ int deg[256];
    __shared__ int ex[256];
    __shared__ int cur[256];
    __shared__ int stage[STAGE_CAP];
    __shared__ int sh_obase;
    int b = blockIdx.x;
    int t = threadIdx.x;
    int ebase = b * CAP;
    int total = cursor[b] - ebase;            // true bucket size (incl overflow)
    int mainsz = total < CAP ? total : CAP;
    int ovfn = ovf_cnt[0];                    // normally 0
    if (t < 256) deg[t] = 0;
    __syncthreads();

    // single read pass: reg-cache + deg count (CAP%4==0 so ebase 16B-aligned)
    unsigned int w[5][4];
    const uint4* b4 = (const uint4*)(binned + ebase);
#pragma unroll
    for (int i = 0; i < 5; ++i) {
        int j4 = t + i * 512;
        int e0 = j4 << 2;
        if (e0 + 3 < mainsz) {
            uint4 v = b4[j4];
            w[i][0] = v.x; w[i][1] = v.y; w[i][2] = v.z; w[i][3] = v.w;
        } else {
#pragma unroll
            for (int cx = 0; cx < 4; ++cx)
                w[i][cx] = (e0 + cx < mainsz) ? binned[ebase + e0 + cx] : 0u;
        }
#pragma unroll
        for (int cx = 0; cx < 4; ++cx)
            if (e0 + cx < mainsz) atomicAdd(&deg[w[i][cx] >> 24], 1);
    }
    for (int i = t; i < ovfn; i += 512)
        if (ovf_b[i] == b) atomicAdd(&deg[ovf_w[i] >> 24], 1);
    __syncthreads();

    // exclusive scan over 256 node degrees (predicated; all threads barrier)
    int d = (t < 256) ? deg[t] : 0;
    if (t < 256) ex[t] = d;
    __syncthreads();
    for (int off = 1; off < 256; off <<= 1) {
        int a = (t < 256 && t >= off) ? ex[t - off] : 0;
        __syncthreads();
        if (t < 256) ex[t] += a;
        __syncthreads();
    }
    int excl = (t < 256) ? (ex[t] - d) : 0;
    if (t == 0) {
        if (total <= CAP) sh_obase = ebase;
        else sh_obase = nb * CAP + atomicAdd(csr_ovf_cur, total);
    }
    __syncthreads();
    int obase = sh_obase;
    int gnode = (b << 8) + t;
    if (t < 256 && gnode < n) {
        rowptr[gnode] = obase + excl;
        rowend[gnode] = obase + excl + d;
        dis[gnode] = rsqrtf((float)d + 1.0f);   // +1 = self-loop
    }
    if (t < 256) cur[t] = excl;
    __syncthreads();

    if (total <= STAGE_CAP) {
        // scatter from registers into LDS stage, then coalesced flush
#pragma unroll
        for (int i = 0; i < 5; ++i) {
            int e0 = (t + i * 512) << 2;
#pragma unroll
            for (int cx = 0; cx < 4; ++cx) {
                if (e0 + cx < mainsz) {
                    unsigned int pk = w[i][cx];
                    stage[atomicAdd(&cur[pk >> 24], 1)] = (int)(pk & 0xffffffu);
                }
            }
        }
        for (int i = t; i < ovfn; i += 512) {
            if (ovf_b[i] == b) {
                unsigned int pk = ovf_w[i];
                stage[atomicAdd(&cur[pk >> 24], 1)] = (int)(pk & 0xffffffu);
            }
        }
        __syncthreads();
        for (int e = t; e < total; e += 512) csr[obase + e] = stage[e];
    } else {  // oversize fallback: direct scatter (correct for any input)
#pragma unroll
        for (int i = 0; i < 5; ++i) {
            int e0 = (t + i * 512) << 2;
#pragma unroll
            for (int cx = 0; cx < 4; ++cx) {
                if (e0 + cx < mainsz) {
                    unsigned int pk = w[i][cx];
                    int pos = atomicAdd(&cur[pk >> 24], 1);
                    csr[obase + pos] = (int)(pk & 0xffffffu);
                }
            }
        }
        for (int i = t; i < ovfn; i += 512) {
            if (ovf_b[i] == b) {
                unsigned int pk = ovf_w[i];
                int pos = atomicAdd(&cur[pk >> 24], 1);
                csr[obase + pos] = (int)(pk & 0xffffffu);
            }
        }
    }
}

// ---------- cooperative fused gather chain (converged structure) ----------
template <int NS, int CBT>
__global__ __launch_bounds__(256, 8) void coop_gather_t(
    const int* __restrict__ rowptr, const int* __restrict__ rowend,
    const int* __restrict__ csr,
    const float* __restrict__ dis, float* __restrict__ qA, float* __restrict__ qB,
    const float* __restrict__ c,
    float* __restrict__ bmin, float* __restrict__ bmax,
    float* __restrict__ out, int n) {
    cg::grid_group grid = cg::this_grid();
    __shared__ float smn[256], smx[256];
    int t = threadIdx.x;
    int lane = t & 15, grp = t >> 4;
    int gid0 = (int)blockIdx.x * 16 + grp;       // node id at sweep 0, stride CBT*16

    int beg[NS], end[NS];
    float dd[NS], qown[NS], vacc[NS];
    float cc[7];
#pragma unroll
    for (int k = 0; k < 7; ++k) cc[k] = c[k];

#pragma unroll
    for (int s = 0; s < NS; ++s) {
        int node = gid0 + s * (CBT * 16);
        bool act = node < n;
        beg[s] = act ? rowptr[node] : 0;
        end[s] = act ? rowend[node] : 0;
        dd[s]  = act ? dis[node] : 0.f;
        qown[s] = dd[s];                 // q0 = dis .* ones
        vacc[s] = cc[0];
    }

    const float* q = dis;
    for (int k = 1; k <= 6; ++k) {
        float* qn = (k & 1) ? qA : qB;
#pragma unroll
        for (int s = 0; s < NS; ++s) {
            float acc = 0.f;
            for (int e = beg[s] + lane; e < end[s]; e += 16)
                acc += q[csr[e]];
#pragma unroll
            for (int off = 8; off > 0; off >>= 1) acc += __shfl_down(acc, off, 16);
            int node = gid0 + s * (CBT * 16);
            if (lane == 0 && node < n) {
                float p = dd[s] * (acc + qown[s]);
                qown[s] = dd[s] * p;
                if (k < 6) qn[node] = qown[s];
                vacc[s] += cc[k] * p;
            }
        }
        if (k < 6) {
            __threadfence();
            grid.sync();
            q = qn;
        }
    }

    // block-local min/max of vacc (lane0s hold real values)
    float mn = 1e30f, mx = -1e30f;
    if (lane == 0) {
#pragma unroll
        for (int s = 0; s < NS; ++s) {
            int node = gid0 + s * (CBT * 16);
            if (node < n) { mn = fminf(mn, vacc[s]); mx = fmaxf(mx, vacc[s]); }
        }
    }
    smn[t] = mn; smx[t] = mx;
    __syncthreads();
    for (int sft = 128; sft > 0; sft >>= 1) {
        if (t < sft) {
            smn[t] = fminf(smn[t], smn[t + sft]);
            smx[t] = fmaxf(smx[t], smx[t + sft]);
        }
        __syncthreads();
    }
    if (t == 0) { bmin[blockIdx.x] = smn[0]; bmax[blockIdx.x] = smx[0]; }
    __threadfence();
    grid.sync();

    // redundant per-block final reduce + normalize
    mn = 1e30f; mx = -1e30f;
    for (int j = t; j < CBT; j += 256) {
        mn = fminf(mn, bmin[j]);
        mx = fmaxf(mx, bmax[j]);
    }
    smn[t] = mn; smx[t] = mx;
    __syncthreads();
    for (int sft = 128; sft > 0; sft >>= 1) {
        if (t < sft) {
            smn[t] = fminf(smn[t], smn[t + sft]);
            smx[t] = fmaxf(smx[t], smx[t + sft]);
        }
        __syncthreads();
    }
    mn = smn[0]; mx = smx[0];
    float inv = 1.0f / (mx - mn + 1e-15f);
    if (lane == 0) {
#pragma unroll
        for (int s = 0; s < NS; ++s) {
            int node = gid0 + s * (CBT * 16);
            if (node < n) out[node] = (vacc[s] - mn) * inv;
        }
    }
}

// ---------- fallback chain (known-good) ----------
__global__ void gather_step(const int* __restrict__ rowptr, const int* __restrict__ rowend,
                            const int* __restrict__ csr,
                            const float* __restrict__ dis, const float* __restrict__ q,
                            const float* __restrict__ c, int k,
                            float* __restrict__ qnext, float* __restrict__ vacc,
                            int n, int first) {
    int tid = blockIdx.x * blockDim.x + threadIdx.x;
    int node = tid >> 4;
    int lane = tid & 15;
    if (node >= n) return;
    int beg = rowptr[node], end = rowend[node];
    float acc = 0.f;
    for (int e = beg + lane; e < end; e += 16) acc += q[csr[e]];
    for (int off = 8; off > 0; off >>= 1) acc += __shfl_down(acc, off, 16);
    if (lane == 0) {
        float d = dis[node];
        float p = d * (acc + q[node]);
        qnext[node] = d * p;
        float add = c[k] * p;
        vacc[node] = first ? (c[0] + add) : (vacc[node] + add);
    }
}

__global__ void gather_last(const int* __restrict__ rowptr, const int* __restrict__ rowend,
                            const int* __restrict__ csr,
                            const float* __restrict__ dis, const float* __restrict__ q,
                            const float* __restrict__ c,
                            float* __restrict__ vacc,
                            float* __restrict__ bmin, float* __restrict__ bmax, int n) {
    __shared__ float smn[TPB], smx[TPB];
    int t = threadIdx.x;
    int tid = blockIdx.x * blockDim.x + t;
    int node = tid >> 4;
    int lane = tid & 15;
    float v = 1e30f;
    bool act = (node < n);
    if (act) {
        int beg = rowptr[node], end = rowend[node];
        float acc = 0.f;
        for (int e = beg + lane; e < end; e += 16) acc += q[csr[e]];
        for (int off = 8; off > 0; off >>= 1) acc += __shfl_down(acc, off, 16);
        if (lane == 0) {
            float d = dis[node];
            float p = d * (acc + q[node]);
            v = vacc[node] + c[6] * p;
            vacc[node] = v;
        }
    }
    smn[t] = (act && lane == 0) ? v : 1e30f;
    smx[t] = (act && lane == 0) ? v : -1e30f;
    __syncthreads();
    for (int s = TPB / 2; s > 0; s >>= 1) {
        if (t < s) { smn[t] = fminf(smn[t], smn[t + s]); smx[t] = fmaxf(smx[t], smx[t + s]); }
        __syncthreads();
    }
    if (t == 0) { bmin[blockIdx.x] = smn[0]; bmax[blockIdx.x] = smx[0]; }
}

__global__ void minmax_final_kernel(const float* __restrict__ bmin, const float* __restrict__ bmax,
                                    int nblk, float* __restrict__ mnmx) {
    __shared__ float smn[TPB], smx[TPB];
    int t = threadIdx.x;
    float mn = 1e30f, mx = -1e30f;
    for (int i = t; i < nblk; i += TPB) {
        mn = fminf(mn, bmin[i]);
        mx = fmaxf(mx, bmax[i]);
    }
    smn[t] = mn; smx[t] = mx;
    __syncthreads();
    for (int s = TPB / 2; s > 0; s >>= 1) {
        if (t < s) { smn[t] = fminf(smn[t], smn[t + s]); smx[t] = fmaxf(smx[t], smx[t + s]); }
        __syncthreads();
    }
    if (t == 0) { mnmx[0] = smn[0]; mnmx[1] = smx[0]; }
}

__global__ void normalize_kernel(const float* __restrict__ v, const float* __restrict__ mnmx,
                                 float* __restrict__ out, int n) {
    int i = blockIdx.x * blockDim.x + threadIdx.x;
    if (i < n) {
        float mn = mnmx[0], mx = mnmx[1];
        out[i] = (v[i] - mn) / (mx - mn + 1e-15f);
    }
}

static inline int cdiv(long long a, int b) { return (int)((a + b - 1) / b); }

extern "C" void kernel_launch(void* const* d_in, const int* in_sizes, int n_in,
                              void* d_out, int out_size, void* d_ws, size_t ws_size,
                              hipStream_t stream) {
    const int N = out_size;               // 100000
    const int E = in_sizes[0] / 2;        // 3200000
    const int* src = (const int*)d_in[0];
    const int* dst = src + E;

    const float* W1 = (const float*)d_in[1];  const float* b1 = (const float*)d_in[2];
    const float* W2 = (const float*)d_in[3];  const float* b2 = (const float*)d_in[4];
    const float* W3 = (const float*)d_in[5];  const float* b3 = (const float*)d_in[6];
    const float* W4 = (const float*)d_in[7];  const float* b4 = (const float*)d_in[8];
    const float* W5 = (const float*)d_in[9];  const float* b5 = (const float*)d_in[10];
    const float* W6 = (const float*)d_in[11]; const float* b6 = (const float*)d_in[12];

    const int nb = (N + 255) >> 8;        // 391 buckets of 256 nodes
    const int gblocks = cdiv((long long)N * 16, TPB);   // 6250
    const size_t nbCAP = (size_t)nb * CAP;

    // workspace layout (16B-aligned arrays first)
    char* p = (char*)d_ws;
    unsigned int* binned = (unsigned int*)p; p += nbCAP * 4;
    int*   csr           = (int*)p;          p += (nbCAP + (size_t)E) * 4;
    unsigned int* ovf_w  = (unsigned int*)p; p += (size_t)E * 4;
    int*   rowptr        = (int*)p;          p += (size_t)N * 4;
    int*   rowend        = (int*)p;          p += (size_t)N * 4;
    float* dis    = (float*)p; p += (size_t)N * 4;
    float* qA     = (float*)p; p += (size_t)N * 4;
    float* qB     = (float*)p; p += (size_t)N * 4;
    float* vacc   = (float*)p; p += (size_t)N * 4;
    float* bmin   = (float*)p; p += (size_t)gblocks * 4;
    float* bmax   = (float*)p; p += (size_t)gblocks * 4;
    float* c      = (float*)p; p += (size_t)8 * 4;
    float* mnmx   = (float*)p; p += 2 * 4;
    int*   cursor = (int*)p;   p += (size_t)512 * 4;
    int*   ovf_cnt = (int*)p;  p += 4;
    int*   csr_ovf_cur = (int*)p; p += 4;
    unsigned short* ovf_b = (unsigned short*)p; p += (size_t)E * 2;

    // ---- CSR build (no hist/scan: fixed-capacity buckets + overflow) ----
    init_kernel<<<2, 256, 0, stream>>>(cursor, nb, ovf_cnt, csr_ovf_cur);
    const int nbA = cdiv(E, BINE);        // 391 binning blocks + 1 coef block
    binA_kernel<<<nbA + 1, BATPB, 0, stream>>>(src, dst, E, cursor, binned,
                                               ovf_w, ovf_b, ovf_cnt,
                                               W1, b1, W2, b2, W3, b3,
                                               W4, b4, W5, b5, W6, b6, c);
    csrB_kernel<<<nb, 512, 0, stream>>>(binned, cursor, ovf_w, ovf_b, ovf_cnt,
                                        csr_ovf_cur, nb, N,
                                        rowptr, rowend, csr, dis);

    // ---- gather chain: coop<4,2048> if 8 blocks/CU fit, else launch chain ----
    constexpr int CB8 = 2048, NS8 = 4;
    int occ = 0;
    hipError_t oerr = hipOccupancyMaxActiveBlocksPerMultiprocessor(
        &occ, (const void*)coop_gather_t<NS8, CB8>, 256, 0);
    bool canCoop = (oerr == hipSuccess) && ((long long)occ * 256 >= CB8) &&
                   (N <= CB8 * 16 * NS8);
    if (canCoop) {
        const int* rp = rowptr; const int* re = rowend; const int* cs = csr;
        const float* dis_c = dis; const float* cc = c;
        float* qA_ = qA; float* qB_ = qB;
        float* bmin_ = bmin; float* bmax_ = bmax;
        float* outp = (float*)d_out;
        int n_ = N;
        void* args[] = { &rp, &re, &cs, &dis_c, &qA_, &qB_, &cc,
                         &bmin_, &bmax_, &outp, &n_ };
        hipLaunchCooperativeKernel((const void*)coop_gather_t<NS8, CB8>,
                                   dim3(CB8), dim3(256), args, 0, stream);
    } else {
        gather_step<<<gblocks, TPB, 0, stream>>>(rowptr, rowend, csr, dis, dis, c, 1, qA, vacc, N, 1);
        gather_step<<<gblocks, TPB, 0, stream>>>(rowptr, rowend, csr, dis, qA,  c, 2, qB, vacc, N, 0);
        gather_step<<<gblocks, TPB, 0, stream>>>(rowptr, rowend, csr, dis, qB,  c, 3, qA, vacc, N, 0);
        gather_step<<<gblocks, TPB, 0, stream>>>(rowptr, rowend, csr, dis, qA,  c, 4, qB, vacc, N, 0);
        gather_step<<<gblocks, TPB, 0, stream>>>(rowptr, rowend, csr, dis, qB,  c, 5, qA, vacc, N, 0);
        gather_last<<<gblocks, TPB, 0, stream>>>(rowptr, rowend, csr, dis, qA, c, vacc, bmin, bmax, N);
        minmax_final_kernel<<<1, TPB, 0, stream>>>(bmin, bmax, gblocks, mnmx);
        normalize_kernel<<<cdiv(N, TPB), TPB, 0, stream>>>(vacc, mnmx, (float*)d_out, N);
    }
}